// Round 2
// baseline (484.212 us; speedup 1.0000x reference)
//
#include <hip/hip_runtime.h>

// out[t, d] = x[t, d] * gain[d]
// gain[d] = sum_n cos(n * OMEGA * DT - eps[n,d] * DT)
// eps[n,d] = floquet_energies[n,d] * (1 + 0.1 * drive_weights[n])
// coupling_matrix unused.
//
// Fully fused, ZERO-workspace version:
//  - blockDim.x = D/4 (=1024 for D=4096), so thread t owns d = 4t..4t+3 for
//    EVERY row. Prologue: thread computes its own 4 gains (fe is 256 KB,
//    L2-resident; 16 vec4 loads + 64 cosf per thread).
//  - Main loop: grid-stride over rows; 1 nontemporal vec4 load + 1
//    nontemporal vec4 store per 32 B of stream. gain lives in 4 VGPRs.
//  - No d_ws usage at all (removes the 1 GiB workspace poison from play).

#define F_DT 0.01f
#define F_OMEGA 1.0f

// clang-native vector type: __builtin_nontemporal_* accepts these
// (HIP_vector_type float4 is rejected — round-1 compile error).
typedef float f32x4 __attribute__((ext_vector_type(4)));

__global__ __launch_bounds__(1024) void fused_rows_kernel(
        const f32x4* __restrict__ x4,
        const f32x4* __restrict__ fe4,
        const float* __restrict__ dw,
        f32x4* __restrict__ out4,
        int M, int Dq, long long n4) {
    const int t = threadIdx.x;  // t < Dq == blockDim.x

    // ---- Prologue: gain for d = 4t .. 4t+3, in registers ----
    f32x4 g = {0.0f, 0.0f, 0.0f, 0.0f};
    #pragma unroll 4
    for (int n = 0; n < M; ++n) {
        f32x4 e = fe4[(long long)n * Dq + t];
        float w = (1.0f + 0.1f * dw[n]) * F_DT;   // eps scale folded with DT
        float a = (float)n * (F_OMEGA * F_DT);
        g.x += cosf(a - e.x * w);
        g.y += cosf(a - e.y * w);
        g.z += cosf(a - e.z * w);
        g.w += cosf(a - e.w * w);
    }

    // ---- Main stream: grid-stride over rows ----
    const long long stride = (long long)gridDim.x * Dq;
    for (long long i = (long long)blockIdx.x * Dq + t; i < n4; i += stride) {
        f32x4 xv = __builtin_nontemporal_load(&x4[i]);
        f32x4 o = xv * g;
        __builtin_nontemporal_store(o, &out4[i]);
    }
}

// Generic fallback (any D / n): recompute gain per element from L2-resident
// fe. Slow path, correctness-only; never taken for the benched shape.
__global__ void fused_scalar_kernel(
        const float* __restrict__ x,
        const float* __restrict__ fe,
        const float* __restrict__ dw,
        float* __restrict__ out,
        int M, int D, long long n) {
    const long long stride = (long long)gridDim.x * blockDim.x;
    for (long long i = (long long)blockIdx.x * blockDim.x + threadIdx.x;
         i < n; i += stride) {
        int d = (int)(i % D);
        float g = 0.0f;
        for (int nn = 0; nn < M; ++nn) {
            float eps = fe[(long long)nn * D + d] * (1.0f + 0.1f * dw[nn]);
            g += cosf((float)nn * (F_OMEGA * F_DT) - eps * F_DT);
        }
        out[i] = x[i] * g;
    }
}

extern "C" void kernel_launch(void* const* d_in, const int* in_sizes, int n_in,
                              void* d_out, int out_size, void* d_ws, size_t ws_size,
                              hipStream_t stream) {
    const float* x  = (const float*)d_in[0];
    const float* fe = (const float*)d_in[1];
    const float* dw = (const float*)d_in[2];
    // d_in[3] = coupling_matrix, unused by the forward

    float* out = (float*)d_out;
    (void)d_ws; (void)ws_size;           // intentionally unused

    int M = in_sizes[2];                 // drive_weights: [M]
    int D = in_sizes[1] / M;             // floquet_energies: [M, D]
    long long n = (long long)in_sizes[0];

    const int Dq = D / 4;
    const bool vec_ok = (D % 4 == 0) && (n % D == 0) &&
                        (Dq >= 64) && (Dq <= 1024) && (Dq % 64 == 0);

    if (vec_ok) {
        long long n4 = n / 4;
        long long rows = n4 / Dq;        // = B*S
        int blocks = (int)(rows < 2048 ? rows : 2048);
        fused_rows_kernel<<<blocks, Dq, 0, stream>>>(
            (const f32x4*)x, (const f32x4*)fe, dw, (f32x4*)out, M, Dq, n4);
    } else {
        int threads = 256;
        long long want = (n + threads - 1) / threads;
        int blocks = (int)(want < 2048 ? want : 2048);
        fused_scalar_kernel<<<blocks, threads, 0, stream>>>(
            x, fe, dw, out, M, D, n);
    }
}

// Round 3
// 450.173 us; speedup vs baseline: 1.0756x; 1.0756x over previous
//
#include <hip/hip_runtime.h>

// out[t, d] = x[t, d] * gain[d]
// gain[d] = sum_n cos(n * OMEGA * DT - eps[n,d] * DT)
// eps[n,d] = floquet_energies[n,d] * (1 + 0.1 * drive_weights[n])
// coupling_matrix unused.
//
// Split structure (round-2 post-mortem: fused-per-block gain recompute cost
// ~60 µs of redundant cosf; the 1 GiB ws-poison fills are unconditional and
// timed, so using d_ws is free):
//   1) gain_kernel: compute gain[0..D) ONCE (65K cosf total) into d_ws.
//   2) scale_rows_kernel: blockDim = D/4, each thread loads its float4 of
//      gain into registers ONCE, then grid-strides rows with exactly
//      1 vec4 load + 1 vec4 store per 32 B of stream (round-0 did 3 VMEM
//      ops per 32 B: x, gain re-load, out).

#define F_DT 0.01f
#define F_OMEGA 1.0f

typedef float f32x4 __attribute__((ext_vector_type(4)));

__global__ void gain_kernel_v4(const f32x4* __restrict__ fe4,
                               const float* __restrict__ dw,
                               f32x4* __restrict__ gain4, int M, int Dq) {
    int t = blockIdx.x * blockDim.x + threadIdx.x;
    if (t >= Dq) return;
    f32x4 g = {0.0f, 0.0f, 0.0f, 0.0f};
    for (int n = 0; n < M; ++n) {
        f32x4 e = fe4[(long long)n * Dq + t];
        float w = (1.0f + 0.1f * dw[n]) * F_DT;   // eps scale folded with DT
        float a = (float)n * (F_OMEGA * F_DT);
        g.x += cosf(a - e.x * w);
        g.y += cosf(a - e.y * w);
        g.z += cosf(a - e.z * w);
        g.w += cosf(a - e.w * w);
    }
    gain4[t] = g;
}

// blockDim.x == Dq (=1024 for D=4096): thread t owns columns 4t..4t+3 of
// every row. Gain is register-resident; stream is 1 load + 1 store per 32 B.
__global__ __launch_bounds__(1024) void scale_rows_kernel(
        const f32x4* __restrict__ x4,
        const f32x4* __restrict__ gain4,
        f32x4* __restrict__ out4,
        int Dq, long long n4) {
    const int t = threadIdx.x;
    const f32x4 g = gain4[t];                      // one 16 B load, L2-hit
    const long long stride = (long long)gridDim.x * Dq;
    for (long long i = (long long)blockIdx.x * Dq + t; i < n4; i += stride) {
        out4[i] = x4[i] * g;
    }
}

// ---- generic fallbacks (any D / n); never taken for the benched shape ----
__global__ void gain_kernel_scalar(const float* __restrict__ fe,
                                   const float* __restrict__ dw,
                                   float* __restrict__ gain, int M, int D) {
    int d = blockIdx.x * blockDim.x + threadIdx.x;
    if (d >= D) return;
    float g = 0.0f;
    for (int n = 0; n < M; ++n) {
        float eps = fe[(long long)n * D + d] * (1.0f + 0.1f * dw[n]);
        g += cosf((float)n * (F_OMEGA * F_DT) - eps * F_DT);
    }
    gain[d] = g;
}

__global__ void scale_kernel_scalar(const float* __restrict__ x,
                                    const float* __restrict__ gain,
                                    float* __restrict__ out,
                                    int D, long long n) {
    const long long stride = (long long)gridDim.x * blockDim.x;
    for (long long i = (long long)blockIdx.x * blockDim.x + threadIdx.x;
         i < n; i += stride) {
        out[i] = x[i] * gain[(int)(i % D)];
    }
}

extern "C" void kernel_launch(void* const* d_in, const int* in_sizes, int n_in,
                              void* d_out, int out_size, void* d_ws, size_t ws_size,
                              hipStream_t stream) {
    const float* x  = (const float*)d_in[0];
    const float* fe = (const float*)d_in[1];
    const float* dw = (const float*)d_in[2];
    // d_in[3] = coupling_matrix, unused by the forward

    float* out  = (float*)d_out;
    float* gain = (float*)d_ws;          // D floats of scratch

    int M = in_sizes[2];                 // drive_weights: [M]
    int D = in_sizes[1] / M;             // floquet_energies: [M, D]
    long long n = (long long)in_sizes[0];

    const int Dq = D / 4;
    const bool vec_ok = (D % 4 == 0) && (n % D == 0) &&
                        (Dq >= 64) && (Dq <= 1024) && (Dq % 64 == 0);

    if (vec_ok) {
        // 1) gain, computed exactly once (D cosf-sums total)
        {
            int threads = 256;
            int blocks = (Dq + threads - 1) / threads;
            gain_kernel_v4<<<blocks, threads, 0, stream>>>(
                (const f32x4*)fe, dw, (f32x4*)gain, M, Dq);
        }
        // 2) stream: register-resident gain, 1 load + 1 store per 32 B
        {
            long long n4 = n / 4;
            long long rows = n4 / Dq;    // = B*S
            int blocks = (int)(rows < 2048 ? rows : 2048);
            scale_rows_kernel<<<blocks, Dq, 0, stream>>>(
                (const f32x4*)x, (const f32x4*)gain, (f32x4*)out, Dq, n4);
        }
    } else {
        {
            int threads = 256;
            int blocks = (D + threads - 1) / threads;
            gain_kernel_scalar<<<blocks, threads, 0, stream>>>(fe, dw, gain, M, D);
        }
        {
            int threads = 256;
            long long want = (n + threads - 1) / threads;
            int blocks = (int)(want < 2048 ? want : 2048);
            scale_kernel_scalar<<<blocks, threads, 0, stream>>>(x, gain, out, D, n);
        }
    }
}

// Round 4
// 430.059 us; speedup vs baseline: 1.1259x; 1.0468x over previous
//
#include <hip/hip_runtime.h>

// out[t, d] = x[t, d] * gain[d]
// gain[d] = sum_n cos(n * OMEGA * DT - eps[n,d] * DT)
// eps[n,d] = floquet_energies[n,d] * (1 + 0.1 * drive_weights[n])
// coupling_matrix unused.
//
// Structure (settled over rounds 0-3):
//  - ~331 µs of the headline is harness workspace re-poison (2x 1 GiB fills,
//    unconditional & timed — proven in round 2 by using zero workspace).
//  - gain kernel: ~4 µs, 65K cosf total, once.
//  - scale kernel: HBM-bound stream. Round-0 shape (256-thr one-shot blocks,
//    3 VMEM/32B with the gain reload an L1 hit) measured best (~94 µs combined);
//    1024-thr grid-stride rounds regressed (~119 µs) — occupancy granularity,
//    not VMEM count, is what matters here. Only change vs round 0:
//    non-temporal x-load/out-store (single-touch stream, keep L2/L3 clean).

#define F_DT 0.01f
#define F_OMEGA 1.0f

typedef float f32x4 __attribute__((ext_vector_type(4)));

__global__ void gain_kernel_v4(const f32x4* __restrict__ fe4,
                               const float* __restrict__ dw,
                               f32x4* __restrict__ gain4, int M, int Dq) {
    int t = blockIdx.x * blockDim.x + threadIdx.x;
    if (t >= Dq) return;
    f32x4 g = {0.0f, 0.0f, 0.0f, 0.0f};
    for (int n = 0; n < M; ++n) {
        f32x4 e = fe4[(long long)n * Dq + t];
        float w = (1.0f + 0.1f * dw[n]) * F_DT;   // eps scale folded with DT
        float a = (float)n * (F_OMEGA * F_DT);
        g.x += cosf(a - e.x * w);
        g.y += cosf(a - e.y * w);
        g.z += cosf(a - e.z * w);
        g.w += cosf(a - e.w * w);
    }
    gain4[t] = g;
}

// Round-0 shape: one float4 per thread, one-shot grid, 256-thread blocks.
__global__ void scale_kernel(const f32x4* __restrict__ x4,
                             const f32x4* __restrict__ gain4,
                             f32x4* __restrict__ out4,
                             long long n4, int Dq) {
    long long i = (long long)blockIdx.x * blockDim.x + threadIdx.x;
    if (i >= n4) return;
    // Dq is a power of two on the fast path (D=4096 -> Dq=1024)
    long long di = ((Dq & (Dq - 1)) == 0) ? (i & (long long)(Dq - 1)) : (i % Dq);
    f32x4 xv = __builtin_nontemporal_load(&x4[i]);   // single-touch stream
    f32x4 gv = gain4[di];                            // 16 KB, L1-resident
    __builtin_nontemporal_store(xv * gv, &out4[i]);
}

// ---- generic fallbacks (any D / n); never taken for the benched shape ----
__global__ void gain_kernel_scalar(const float* __restrict__ fe,
                                   const float* __restrict__ dw,
                                   float* __restrict__ gain, int M, int D) {
    int d = blockIdx.x * blockDim.x + threadIdx.x;
    if (d >= D) return;
    float g = 0.0f;
    for (int n = 0; n < M; ++n) {
        float eps = fe[(long long)n * D + d] * (1.0f + 0.1f * dw[n]);
        g += cosf((float)n * (F_OMEGA * F_DT) - eps * F_DT);
    }
    gain[d] = g;
}

__global__ void scale_kernel_scalar(const float* __restrict__ x,
                                    const float* __restrict__ gain,
                                    float* __restrict__ out,
                                    int D, long long n) {
    const long long stride = (long long)gridDim.x * blockDim.x;
    for (long long i = (long long)blockIdx.x * blockDim.x + threadIdx.x;
         i < n; i += stride) {
        out[i] = x[i] * gain[(int)(i % D)];
    }
}

extern "C" void kernel_launch(void* const* d_in, const int* in_sizes, int n_in,
                              void* d_out, int out_size, void* d_ws, size_t ws_size,
                              hipStream_t stream) {
    const float* x  = (const float*)d_in[0];
    const float* fe = (const float*)d_in[1];
    const float* dw = (const float*)d_in[2];
    // d_in[3] = coupling_matrix, unused by the forward

    float* out  = (float*)d_out;
    float* gain = (float*)d_ws;          // D floats of scratch

    int M = in_sizes[2];                 // drive_weights: [M]
    int D = in_sizes[1] / M;             // floquet_energies: [M, D]
    long long n = (long long)in_sizes[0];

    const bool vec_ok = (D % 4 == 0) && (n % 4 == 0);

    if (vec_ok) {
        int Dq = D / 4;
        // 1) gain, computed exactly once
        {
            int threads = 256;
            int blocks = (Dq + threads - 1) / threads;
            gain_kernel_v4<<<blocks, threads, 0, stream>>>(
                (const f32x4*)fe, dw, (f32x4*)gain, M, Dq);
        }
        // 2) stream scale, round-0 shape + non-temporal stream ops
        {
            long long n4 = n / 4;
            int threads = 256;
            long long blocks = (n4 + threads - 1) / threads;
            scale_kernel<<<(int)blocks, threads, 0, stream>>>(
                (const f32x4*)x, (const f32x4*)gain, (f32x4*)out, n4, Dq);
        }
    } else {
        {
            int threads = 256;
            int blocks = (D + threads - 1) / threads;
            gain_kernel_scalar<<<blocks, threads, 0, stream>>>(fe, dw, gain, M, D);
        }
        {
            int threads = 256;
            long long want = (n + threads - 1) / threads;
            int blocks = (int)(want < 2048 ? want : 2048);
            scale_kernel_scalar<<<blocks, threads, 0, stream>>>(x, gain, out, D, n);
        }
    }
}